// Round 3
// baseline (337.983 us; speedup 1.0000x reference)
//
#include <hip/hip_runtime.h>

typedef unsigned short u16;
typedef short v8s __attribute__((ext_vector_type(8)));
typedef float v4f __attribute__((ext_vector_type(4)));
typedef float v16f __attribute__((ext_vector_type(16)));

typedef __attribute__((address_space(3))) u16* lptr_t;
typedef const __attribute__((address_space(1))) void* gptr_t;

__device__ __forceinline__ u16 f2b(float f) {
  unsigned int u = __float_as_uint(f);
  u += 0x7fff + ((u >> 16) & 1);   // RNE
  return (u16)(u >> 16);
}

// fp32 -> bf16 for q,k,v in one launch (blocks 0..4095 q, ..8191 k, ..12287 v)
__global__ __launch_bounds__(256) void conv3_bf16(const float* __restrict__ q,
                                                  const float* __restrict__ k,
                                                  const float* __restrict__ v,
                                                  u16* __restrict__ qd,
                                                  u16* __restrict__ kd,
                                                  u16* __restrict__ vd) {
  int blk = blockIdx.x;
  const float* s; u16* d;
  if (blk < 4096)      { s = q; d = qd; }
  else if (blk < 8192) { s = k; d = kd; blk -= 4096; }
  else                 { s = v; d = vd; blk -= 8192; }
  int i = (blk * 256 + threadIdx.x) * 8;
  float4 a = *(const float4*)&s[i];
  float4 b = *(const float4*)&s[i + 4];
  union { uint4 v4; u16 u[8]; } p;
  p.u[0] = f2b(a.x); p.u[1] = f2b(a.y); p.u[2] = f2b(a.z); p.u[3] = f2b(a.w);
  p.u[4] = f2b(b.x); p.u[5] = f2b(b.y); p.u[6] = f2b(b.z); p.u[7] = f2b(b.w);
  *(uint4*)&d[i] = p.v4;
}

// All three weight transposes in one launch.
__global__ __launch_bounds__(256) void transp3_w(const float* __restrict__ Wq,
                                                 const float* __restrict__ Wk,
                                                 const float* __restrict__ Wv,
                                                 u16* __restrict__ wt) {
  __shared__ u16 tile[64][65];
  int blk = blockIdx.x;
  const float* W; int N; u16* dst;
  if (blk < 1024)      { W = Wq; N = 2048; dst = wt; }
  else if (blk < 1536) { W = Wk; N = 1024; dst = wt + (size_t)2048 * 2048; blk -= 1024; }
  else                 { W = Wv; N = 1024; dst = wt + (size_t)3072 * 2048; blk -= 1536; }
  const int k0 = (blk & 31) * 64;
  const int n0 = (blk >> 5) * 64;
  const int t = threadIdx.x;
#pragma unroll
  for (int i = 0; i < 2; ++i) {
    int chunk = i * 256 + t;
    int kr = chunk >> 3;
    int nc = (chunk & 7) * 8;
    float4 a = *(const float4*)&W[(size_t)(k0 + kr) * N + n0 + nc];
    float4 b = *(const float4*)&W[(size_t)(k0 + kr) * N + n0 + nc + 4];
    tile[kr][nc + 0] = f2b(a.x); tile[kr][nc + 1] = f2b(a.y);
    tile[kr][nc + 2] = f2b(a.z); tile[kr][nc + 3] = f2b(a.w);
    tile[kr][nc + 4] = f2b(b.x); tile[kr][nc + 5] = f2b(b.y);
    tile[kr][nc + 6] = f2b(b.z); tile[kr][nc + 7] = f2b(b.w);
  }
  __syncthreads();
#pragma unroll
  for (int i = 0; i < 2; ++i) {
    int chunk = i * 256 + t;
    int nr = chunk >> 3;
    int kc = (chunk & 7) * 8;
    union { uint4 v; u16 u[8]; } cv;
#pragma unroll
    for (int j = 0; j < 8; ++j) cv.u[j] = tile[kc + j][nr];
    *(uint4*)&dst[(size_t)(n0 + nr) * 2048 + k0 + kc] = cv.v;
  }
}

// =========================================================================
// Fused QKV projection GEMM — 256x256 tile, BK=64, 8-phase schedule
// (T2 swizzle + T3/T4 counted vmcnt + T5 setprio), 512 threads, 8 waves
// (2M x 4N), double-buffered 128 KiB LDS. Q output pre-scaled by 1/sqrt(128).
// Resubmitted unchanged from round 2 (ledger re-audited: barrier counts
// uniform, vmcnt(6) retires exactly one K-tile per PHASE_END_V, all LDS
// WAR hazards covered by lgkmcnt(0)-before-barrier; container failure
// attributed to infra).
// =========================================================================
__global__ __launch_bounds__(512, 2) void qkv_gemm8(const u16* __restrict__ qbf,
                                                    const u16* __restrict__ kbf,
                                                    const u16* __restrict__ vbf,
                                                    const u16* __restrict__ wt_all,
                                                    const float* __restrict__ bq,
                                                    const float* __restrict__ bk,
                                                    const float* __restrict__ bv,
                                                    u16* __restrict__ qp,
                                                    u16* __restrict__ kp,
                                                    u16* __restrict__ vpt) {
  __shared__ __align__(16) u16 A_sh[2][16384];   // [buf][256*64]
  __shared__ __align__(16) u16 B_sh[2][16384];

  const int bid = blockIdx.x;                 // 256 blocks
  const int wg = (bid & 7) * 32 + (bid >> 3); // XCD-chunked swizzle (256%8==0)
  const int m0 = (wg >> 4) * 256;
  const int n0 = (wg & 15) * 256;

  const int t = threadIdx.x;
  const int w = t >> 6, lane = t & 63;
  const int quad = lane >> 4, l16 = lane & 15;
  const int wr = w >> 2, wc = w & 3;          // 2 x 4 wave grid

  const u16* Abase; const float* bias; int region, nloc0;
  if (n0 < 2048)      { Abase = qbf; bias = bq; region = 0; nloc0 = n0; }
  else if (n0 < 3072) { Abase = kbf; bias = bk; region = 1; nloc0 = n0 - 2048; }
  else                { Abase = vbf; bias = bv; region = 2; nloc0 = n0 - 3072; }

  const u16* GA = Abase + (size_t)m0 * 2048;
  const u16* GB = wt_all + (size_t)n0 * 2048;

  // per-thread stage offsets: [sub][j] (j = two 8KB loads per half-tile)
  int offA[2][2], ldsA[2][2], offB[2][2], ldsB[2][2];
#pragma unroll
  for (int s_ = 0; s_ < 2; ++s_)
#pragma unroll
    for (int j = 0; j < 2; ++j) {
      int r0a = j * 128 + s_ * 64 + w * 8;
      int ra = r0a + (lane >> 3);
      offA[s_][j] = ra * 2048 + (((lane & 7) ^ (((ra >> 2) & 1) << 1)) << 3);
      ldsA[s_][j] = r0a * 64 + lane * 8;
      int r0b = j * 128 + s_ * 32 + (w >> 2) * 64 + (w & 3) * 8;
      int rb = r0b + (lane >> 3);
      offB[s_][j] = rb * 2048 + (((lane & 7) ^ (((rb >> 2) & 1) << 1)) << 3);
      ldsB[s_][j] = r0b * 64 + lane * 8;
    }

  // swizzled ds_read col offsets (u16 units); row-bit2 == (l16>>2)&1 always
  int colK[2];
#pragma unroll
  for (int kk = 0; kk < 2; ++kk)
    colK[kk] = (kk * 32 + quad * 8) ^ (((l16 >> 2) & 1) << 4);

#define ST_A(BUF, KEL, S_)                                                              \
  do {                                                                                  \
    _Pragma("unroll") for (int j_ = 0; j_ < 2; ++j_) {                                  \
      const u16* g_ = GA + (KEL) + offA[S_][j_];                                        \
      lptr_t l_ = (lptr_t)&A_sh[BUF][ldsA[S_][j_]];                                     \
      __builtin_amdgcn_global_load_lds((gptr_t)g_,                                      \
                                       (__attribute__((address_space(3))) void*)l_,     \
                                       16, 0, 0);                                       \
    }                                                                                   \
  } while (0)

#define ST_B(BUF, KEL, S_)                                                              \
  do {                                                                                  \
    _Pragma("unroll") for (int j_ = 0; j_ < 2; ++j_) {                                  \
      const u16* g_ = GB + (KEL) + offB[S_][j_];                                        \
      lptr_t l_ = (lptr_t)&B_sh[BUF][ldsB[S_][j_]];                                     \
      __builtin_amdgcn_global_load_lds((gptr_t)g_,                                      \
                                       (__attribute__((address_space(3))) void*)l_,     \
                                       16, 0, 0);                                       \
    }                                                                                   \
  } while (0)

#define RD_A(BUF, MS)                                                                   \
  do {                                                                                  \
    const int rb_ = wr * 128 + (MS) * 64;                                               \
    _Pragma("unroll") for (int m_ = 0; m_ < 4; ++m_)                                    \
    _Pragma("unroll") for (int kk_ = 0; kk_ < 2; ++kk_)                                 \
      a[m_][kk_] = *(const v8s*)&A_sh[BUF][(rb_ + m_ * 16 + l16) * 64 + colK[kk_]];     \
  } while (0)

#define RD_B(BUF, NS)                                                                   \
  do {                                                                                  \
    const int rb_ = wc * 64 + (NS) * 32;                                                \
    _Pragma("unroll") for (int n_ = 0; n_ < 2; ++n_)                                    \
    _Pragma("unroll") for (int kk_ = 0; kk_ < 2; ++kk_)                                 \
      b[n_][kk_] = *(const v8s*)&B_sh[BUF][(rb_ + n_ * 16 + l16) * 64 + colK[kk_]];     \
  } while (0)

#define MM(MS, NS)                                                                      \
  do {                                                                                  \
    __builtin_amdgcn_s_setprio(1);                                                      \
    _Pragma("unroll") for (int kk_ = 0; kk_ < 2; ++kk_)                                 \
    _Pragma("unroll") for (int m_ = 0; m_ < 4; ++m_)                                    \
    _Pragma("unroll") for (int n_ = 0; n_ < 2; ++n_)                                    \
      acc[(MS) * 4 + m_][(NS) * 2 + n_] = __builtin_amdgcn_mfma_f32_16x16x32_bf16(      \
          a[m_][kk_], b[n_][kk_], acc[(MS) * 4 + m_][(NS) * 2 + n_], 0, 0, 0);          \
    __builtin_amdgcn_s_setprio(0);                                                      \
  } while (0)

#define PHASE_MID()                                                                     \
  do {                                                                                  \
    asm volatile("" ::: "memory");                                                      \
    __builtin_amdgcn_s_barrier();                                                       \
    asm volatile("s_waitcnt lgkmcnt(0)" ::: "memory");                                  \
    __builtin_amdgcn_sched_barrier(0);                                                  \
  } while (0)

#define PHASE_END()                                                                     \
  do {                                                                                  \
    asm volatile("" ::: "memory");                                                      \
    __builtin_amdgcn_s_barrier();                                                       \
    __builtin_amdgcn_sched_barrier(0);                                                  \
  } while (0)

#define PHASE_END_V()                                                                   \
  do {                                                                                  \
    asm volatile("s_waitcnt vmcnt(6)" ::: "memory");                                    \
    __builtin_amdgcn_s_barrier();                                                       \
    __builtin_amdgcn_sched_barrier(0);                                                  \
  } while (0)

  v4f acc[8][4] = {};
  v8s a[4][2], b[2][2];

  // ---- prologue: kt0 fully (Aa,Bg,Ab,Bd) + kt1 (Bg,Ab,Bd); Aa(kt1) at P1.
  ST_A(0, 0, 0); ST_B(0, 0, 0); ST_A(0, 0, 1); ST_B(0, 0, 1);
  ST_B(1, 64, 0); ST_A(1, 64, 1); ST_B(1, 64, 1);
  asm volatile("s_waitcnt vmcnt(6)" ::: "memory");   // kt0's 8 loads landed
  __builtin_amdgcn_s_barrier();
  __builtin_amdgcn_sched_barrier(0);

  for (int it = 0; it < 16; ++it) {
    const int k1 = (2 * it + 1) * 64;            // <= 31*64, never wraps
    const int k2 = ((2 * it + 2) & 31) * 64;     // wraps harmlessly on it=15
    const int k3 = ((2 * it + 3) & 31) * 64;
    // ---- K-tile 2it (buf0)
    RD_A(0, 0); RD_B(0, 0); ST_A(1, k1, 0); PHASE_MID(); MM(0, 0); PHASE_END();
    RD_A(0, 1);             ST_B(0, k2, 0); PHASE_MID(); MM(1, 0); PHASE_END();
    RD_B(0, 1);             ST_A(0, k2, 1); PHASE_MID(); MM(1, 1); PHASE_END();
    RD_A(0, 0);             ST_B(0, k2, 1); PHASE_MID(); MM(0, 1); PHASE_END_V();
    // ---- K-tile 2it+1 (buf1)
    RD_A(1, 0); RD_B(1, 0); ST_A(0, k2, 0); PHASE_MID(); MM(0, 0); PHASE_END();
    RD_A(1, 1);             ST_B(1, k3, 0); PHASE_MID(); MM(1, 0); PHASE_END();
    RD_B(1, 1);             ST_A(1, k3, 1); PHASE_MID(); MM(1, 1); PHASE_END();
    RD_A(1, 0);             ST_B(1, k3, 1); PHASE_MID(); MM(0, 1); PHASE_END_V();
  }

#undef ST_A
#undef ST_B
#undef RD_A
#undef RD_B
#undef MM
#undef PHASE_MID
#undef PHASE_END
#undef PHASE_END_V

  // ---- epilogue: bias + per-region store (same mapping as before)
#pragma unroll
  for (int n = 0; n < 4; ++n) {
    int nl = nloc0 + wc * 64 + n * 16 + l16;
    float bvl = bias[nl];
    if (region == 0) {
#pragma unroll
      for (int m = 0; m < 8; ++m)
#pragma unroll
        for (int r = 0; r < 4; ++r) {
          int mg = m0 + wr * 128 + m * 16 + quad * 4 + r;
          qp[(size_t)mg * 2048 + nl] = f2b((acc[m][n][r] + bvl) * 0.08838834764831845f);
        }
    } else if (region == 1) {
#pragma unroll
      for (int m = 0; m < 8; ++m)
#pragma unroll
        for (int r = 0; r < 4; ++r) {
          int mg = m0 + wr * 128 + m * 16 + quad * 4 + r;
          kp[(size_t)mg * 1024 + nl] = f2b(acc[m][n][r] + bvl);
        }
    } else {
      int g = nl >> 7, d = nl & 127;
#pragma unroll
      for (int m = 0; m < 8; ++m) {
        int mb = m0 + wr * 128 + m * 16 + quad * 4;
        int bb = mb >> 11, s = mb & 2047;
        ushort4 pk;
        pk.x = f2b(acc[m][n][0] + bvl);
        pk.y = f2b(acc[m][n][1] + bvl);
        pk.z = f2b(acc[m][n][2] + bvl);
        pk.w = f2b(acc[m][n][3] + bvl);
        *(ushort4*)&vpt[(((size_t)bb * 8 + g) * 128 + d) * 2048 + s] = pk;
      }
    }
  }
}

// =========================================================================
// GQA attention v2 — unchanged from round 1 (passed, ~sub-117us).
// =========================================================================
__global__ __launch_bounds__(256, 2) void gqa_attn2(const u16* __restrict__ qp,
                                                    const u16* __restrict__ kp,
                                                    const u16* __restrict__ vpt,
                                                    float* __restrict__ out) {
  __shared__ __align__(16) u16 K_sh[2][64 * 128];
  __shared__ __align__(16) u16 V_sh[2][128 * 64];

  const int qtile = blockIdx.x;   // 16 tiles of 128 q-rows
  const int head = blockIdx.y;    // 16
  const int batch = blockIdx.z;   // 2
  const int g = head >> 1;
  const int q0 = qtile * 128;

  const u16* qpb = qp + (size_t)batch * 2048 * 2048;
  const u16* kpb = kp + (size_t)batch * 2048 * 1024;
  const u16* vptb = vpt + (size_t)batch * 8 * 128 * 2048;
  float* outb = out + (size_t)batch * 2048 * 2048;

  const int t = threadIdx.x;
  const int wave = t >> 6, lane = t & 63;
  const int l = lane & 31, h = lane >> 5;

  v8s qf[8];
  {
    const u16* qrow = &qpb[(size_t)(q0 + wave * 32 + l) * 2048 + head * 128];
#pragma unroll
    for (int ks = 0; ks < 8; ++ks)
      qf[ks] = *(const v8s*)&qrow[ks * 16 + h * 8];
  }

  int colK[8];
#pragma unroll
  for (int ks = 0; ks < 8; ++ks) colK[ks] = ((2 * ks + h) ^ (l & 7)) * 8;

  int koff[4], voff[4];
#pragma unroll
  for (int i = 0; i < 4; ++i) {
    int krow = wave * 16 + i * 4 + (lane >> 4);
    int kg = (lane & 15) ^ (krow & 7);
    koff[i] = krow * 1024 + g * 128 + kg * 8;
    int vrow = wave * 32 + i * 8 + (lane >> 3);
    int vg = (lane & 7) ^ (vrow & 7);
    voff[i] = (g * 128 + vrow) * 2048 + vg * 8;
  }

#define STAGE_KV(BUF, S0)                                                               \
  do {                                                                                  \
    _Pragma("unroll") for (int i_ = 0; i_ < 4; ++i_) {                                  \
      const u16* gk_ = kpb + (size_t)(S0) * 1024 + koff[i_];                            \
      lptr_t lk_ = (lptr_t)&K_sh[BUF][(wave * 16 + i_ * 4) * 128] + lane * 8;           \
      __builtin_amdgcn_global_load_lds((gptr_t)gk_,                                     \
                                       (__attribute__((address_space(3))) void*)lk_,    \
                                       16, 0, 0);                                       \
      const u16* gv_ = vptb + voff[i_] + (S0);                                          \
      lptr_t lv_ = (lptr_t)&V_sh[BUF][(wave * 32 + i_ * 8) * 64] + lane * 8;            \
      __builtin_amdgcn_global_load_lds((gptr_t)gv_,                                     \
                                       (__attribute__((address_space(3))) void*)lv_,    \
                                       16, 0, 0);                                       \
    }                                                                                   \
  } while (0)

  v16f o_acc[4] = {};
  float rs = 0.0f;

  STAGE_KV(0, 0);
  __syncthreads();

  int cur = 0;
  for (int sc = 0; sc < 32; ++sc) {
    if (sc < 31) STAGE_KV(cur ^ 1, (sc + 1) * 64);

    v16f sacc[2] = {};
    __builtin_amdgcn_s_setprio(1);
#pragma unroll
    for (int kb = 0; kb < 2; ++kb)
#pragma unroll
      for (int ks = 0; ks < 8; ++ks) {
        v8s kf = *(const v8s*)&K_sh[cur][(kb * 32 + l) * 128 + colK[ks]];
        sacc[kb] = __builtin_amdgcn_mfma_f32_32x32x16_bf16(kf, qf[ks], sacc[kb], 0, 0, 0);
      }
    __builtin_amdgcn_s_setprio(0);

    unsigned int wv[16];
#pragma unroll
    for (int kb = 0; kb < 2; ++kb)
#pragma unroll
      for (int p = 0; p < 8; ++p) {
        float e0 = __expf(sacc[kb][2 * p]);
        float e1 = __expf(sacc[kb][2 * p + 1]);
        rs += e0 + e1;
        asm("v_cvt_pk_bf16_f32 %0, %1, %2" : "=v"(wv[kb * 8 + p]) : "v"(e0), "v"(e1));
      }

    v8s pa[4];
#pragma unroll
    for (int j = 0; j < 4; ++j) {
      unsigned int a = wv[j * 4 + 0], c = wv[j * 4 + 1];
      unsigned int b = wv[j * 4 + 2], d = wv[j * 4 + 3];
      asm("v_permlane32_swap_b32 %0, %1" : "+v"(a), "+v"(b));
      asm("v_permlane32_swap_b32 %0, %1" : "+v"(c), "+v"(d));
      union { unsigned int u[4]; v8s s; } pk;
      pk.u[0] = a; pk.u[1] = c; pk.u[2] = b; pk.u[3] = d;
      pa[j] = pk.s;
    }

    __builtin_amdgcn_s_setprio(1);
#pragma unroll
    for (int j = 0; j < 4; ++j)
#pragma unroll
      for (int db = 0; db < 4; ++db) {
        v8s vf = *(const v8s*)&V_sh[cur][(db * 32 + l) * 64 + colK[j]];
        o_acc[db] = __builtin_amdgcn_mfma_f32_32x32x16_bf16(pa[j], vf, o_acc[db], 0, 0, 0);
      }
    __builtin_amdgcn_s_setprio(0);

    __syncthreads();
    cur ^= 1;
  }

  float rst = rs + __shfl_xor(rs, 32, 64);
  float inv = 1.0f / rst;
#pragma unroll
  for (int r = 0; r < 16; ++r) {
    int qpat = (r & 3) + 8 * (r >> 2) + 4 * h;
    float invq = __shfl(inv, qpat, 64);
    int qrow = q0 + wave * 32 + qpat;
    float* orow = &outb[(size_t)qrow * 2048 + head * 128 + l];
#pragma unroll
    for (int db = 0; db < 4; ++db)
      orow[db * 32] = o_acc[db][r] * invq;
  }
#undef STAGE_KV
}

// =========================================================================
extern "C" void kernel_launch(void* const* d_in, const int* in_sizes, int n_in,
                              void* d_out, int out_size, void* d_ws, size_t ws_size,
                              hipStream_t stream) {
  const float* q  = (const float*)d_in[0];
  const float* k  = (const float*)d_in[1];
  const float* v  = (const float*)d_in[2];
  const float* Wq = (const float*)d_in[3];
  const float* bq = (const float*)d_in[4];
  const float* Wk = (const float*)d_in[5];
  const float* bk = (const float*)d_in[6];
  const float* Wv = (const float*)d_in[7];
  const float* bv = (const float*)d_in[8];
  float* out = (float*)d_out;
  char* ws = (char*)d_ws;

  u16* qbf    = (u16*)(ws + 0);          // [4096][2048] bf16
  u16* kbf    = (u16*)(ws + 16777216);
  u16* vbf    = (u16*)(ws + 33554432);
  u16* wt_all = (u16*)(ws + 50331648);   // [4096][2048] (Wq^T|Wk^T|Wv^T)
  u16* qp     = (u16*)(ws + 67108864);   // [4096][2048] (Q pre-scaled)
  u16* kp     = (u16*)(ws + 83886080);   // [4096][1024]
  u16* vpt    = (u16*)(ws + 92274688);   // [2][8][128][2048]

  conv3_bf16<<<12288, 256, 0, stream>>>(q, k, v, qbf, kbf, vbf);
  transp3_w<<<2048, 256, 0, stream>>>(Wq, Wk, Wv, wt_all);
  qkv_gemm8<<<256, 512, 0, stream>>>(qbf, kbf, vbf, wt_all,
                                     bq, bk, bv, qp, kp, vpt);
  gqa_attn2<<<dim3(16, 16, 2), 256, 0, stream>>>(qp, kp, vpt, out);
}

// Round 4
// 320.276 us; speedup vs baseline: 1.0553x; 1.0553x over previous
//
#include <hip/hip_runtime.h>

typedef unsigned short u16;
typedef short v8s __attribute__((ext_vector_type(8)));
typedef float v4f __attribute__((ext_vector_type(4)));
typedef float v16f __attribute__((ext_vector_type(16)));

typedef __attribute__((address_space(3))) u16* lptr_t;
typedef const __attribute__((address_space(1))) void* gptr_t;

__device__ __forceinline__ u16 f2b(float f) {
  unsigned int u = __float_as_uint(f);
  u += 0x7fff + ((u >> 16) & 1);   // RNE
  return (u16)(u >> 16);
}

// fp32 -> bf16 for q,k,v in one launch (blocks 0..4095 q, ..8191 k, ..12287 v)
__global__ __launch_bounds__(256) void conv3_bf16(const float* __restrict__ q,
                                                  const float* __restrict__ k,
                                                  const float* __restrict__ v,
                                                  u16* __restrict__ qd,
                                                  u16* __restrict__ kd,
                                                  u16* __restrict__ vd) {
  int blk = blockIdx.x;
  const float* s; u16* d;
  if (blk < 4096)      { s = q; d = qd; }
  else if (blk < 8192) { s = k; d = kd; blk -= 4096; }
  else                 { s = v; d = vd; blk -= 8192; }
  int i = (blk * 256 + threadIdx.x) * 8;
  float4 a = *(const float4*)&s[i];
  float4 b = *(const float4*)&s[i + 4];
  union { uint4 v4; u16 u[8]; } p;
  p.u[0] = f2b(a.x); p.u[1] = f2b(a.y); p.u[2] = f2b(a.z); p.u[3] = f2b(a.w);
  p.u[4] = f2b(b.x); p.u[5] = f2b(b.y); p.u[6] = f2b(b.z); p.u[7] = f2b(b.w);
  *(uint4*)&d[i] = p.v4;
}

// All three weight transposes in one launch.
__global__ __launch_bounds__(256) void transp3_w(const float* __restrict__ Wq,
                                                 const float* __restrict__ Wk,
                                                 const float* __restrict__ Wv,
                                                 u16* __restrict__ wt) {
  __shared__ u16 tile[64][65];
  int blk = blockIdx.x;
  const float* W; int N; u16* dst;
  if (blk < 1024)      { W = Wq; N = 2048; dst = wt; }
  else if (blk < 1536) { W = Wk; N = 1024; dst = wt + (size_t)2048 * 2048; blk -= 1024; }
  else                 { W = Wv; N = 1024; dst = wt + (size_t)3072 * 2048; blk -= 1536; }
  const int k0 = (blk & 31) * 64;
  const int n0 = (blk >> 5) * 64;
  const int t = threadIdx.x;
#pragma unroll
  for (int i = 0; i < 2; ++i) {
    int chunk = i * 256 + t;
    int kr = chunk >> 3;
    int nc = (chunk & 7) * 8;
    float4 a = *(const float4*)&W[(size_t)(k0 + kr) * N + n0 + nc];
    float4 b = *(const float4*)&W[(size_t)(k0 + kr) * N + n0 + nc + 4];
    tile[kr][nc + 0] = f2b(a.x); tile[kr][nc + 1] = f2b(a.y);
    tile[kr][nc + 2] = f2b(a.z); tile[kr][nc + 3] = f2b(a.w);
    tile[kr][nc + 4] = f2b(b.x); tile[kr][nc + 5] = f2b(b.y);
    tile[kr][nc + 6] = f2b(b.z); tile[kr][nc + 7] = f2b(b.w);
  }
  __syncthreads();
#pragma unroll
  for (int i = 0; i < 2; ++i) {
    int chunk = i * 256 + t;
    int nr = chunk >> 3;
    int kc = (chunk & 7) * 8;
    union { uint4 v; u16 u[8]; } cv;
#pragma unroll
    for (int j = 0; j < 8; ++j) cv.u[j] = tile[kc + j][nr];
    *(uint4*)&dst[(size_t)(n0 + nr) * 2048 + k0 + kc] = cv.v;
  }
}

// =========================================================================
// Fused QKV projection GEMM — 256x256 tile, BK=64, 8-phase schedule.
// Round-4 changes vs round-3:
//  (a) FULL 3-bit XOR swizzle: col granule g (of 8 bf16 = 16B) stored at
//      g ^ (row&7). Lanes 0..7 of a column-slice read hit 8 distinct
//      granules = all 32 banks -> conflict-free (was 1-bit ~4-way).
//      Inverse-swizzled global_load_lds source + swizzled ds_read col
//      (same involution both sides, rule #21).
//  (b) Dedicated a0/a1 register sets: P4/P8 re-read of A-sub0 eliminated
//      (32 -> 24 ds_read_b128 per K-tile per wave).
// vmcnt(6) ledger and barrier structure unchanged from the audited r3.
// =========================================================================
__global__ __launch_bounds__(512, 2) void qkv_gemm8(const u16* __restrict__ qbf,
                                                    const u16* __restrict__ kbf,
                                                    const u16* __restrict__ vbf,
                                                    const u16* __restrict__ wt_all,
                                                    const float* __restrict__ bq,
                                                    const float* __restrict__ bk,
                                                    const float* __restrict__ bv,
                                                    u16* __restrict__ qp,
                                                    u16* __restrict__ kp,
                                                    u16* __restrict__ vpt) {
  __shared__ __align__(16) u16 A_sh[2][16384];   // [buf][256*64]
  __shared__ __align__(16) u16 B_sh[2][16384];

  const int bid = blockIdx.x;                 // 256 blocks
  const int wg = (bid & 7) * 32 + (bid >> 3); // XCD-chunked swizzle (256%8==0)
  const int m0 = (wg >> 4) * 256;
  const int n0 = (wg & 15) * 256;

  const int t = threadIdx.x;
  const int w = t >> 6, lane = t & 63;
  const int quad = lane >> 4, l16 = lane & 15;
  const int wr = w >> 2, wc = w & 3;          // 2 x 4 wave grid

  const u16* Abase; const float* bias; int region, nloc0;
  if (n0 < 2048)      { Abase = qbf; bias = bq; region = 0; nloc0 = n0; }
  else if (n0 < 3072) { Abase = kbf; bias = bk; region = 1; nloc0 = n0 - 2048; }
  else                { Abase = vbf; bias = bv; region = 2; nloc0 = n0 - 3072; }

  const u16* GA = Abase + (size_t)m0 * 2048;
  const u16* GB = wt_all + (size_t)n0 * 2048;

  // per-thread stage offsets: [sub][j]; source col-granule pre-swizzled by
  // full (row&7) so linear LDS dest ends up holding g at slot g^(row&7).
  int offA[2][2], ldsA[2][2], offB[2][2], ldsB[2][2];
#pragma unroll
  for (int s_ = 0; s_ < 2; ++s_)
#pragma unroll
    for (int j = 0; j < 2; ++j) {
      int r0a = j * 128 + s_ * 64 + w * 8;
      int ra = r0a + (lane >> 3);
      offA[s_][j] = ra * 2048 + (((lane & 7) ^ (ra & 7)) << 3);
      ldsA[s_][j] = r0a * 64 + lane * 8;
      int r0b = j * 128 + s_ * 32 + (w >> 2) * 64 + (w & 3) * 8;
      int rb = r0b + (lane >> 3);
      offB[s_][j] = rb * 2048 + (((lane & 7) ^ (rb & 7)) << 3);
      ldsB[s_][j] = r0b * 64 + lane * 8;
    }

  // swizzled ds_read col offsets (u16 units): granule (kk*4+quad)^(row&7),
  // and row&7 == l16&7 for every fragment row this lane touches.
  int colR[2];
#pragma unroll
  for (int kk = 0; kk < 2; ++kk)
    colR[kk] = ((kk * 4 + quad) ^ (l16 & 7)) << 3;

#define ST_A(BUF, KEL, S_)                                                              \
  do {                                                                                  \
    _Pragma("unroll") for (int j_ = 0; j_ < 2; ++j_) {                                  \
      const u16* g_ = GA + (KEL) + offA[S_][j_];                                        \
      lptr_t l_ = (lptr_t)&A_sh[BUF][ldsA[S_][j_]];                                     \
      __builtin_amdgcn_global_load_lds((gptr_t)g_,                                      \
                                       (__attribute__((address_space(3))) void*)l_,     \
                                       16, 0, 0);                                       \
    }                                                                                   \
  } while (0)

#define ST_B(BUF, KEL, S_)                                                              \
  do {                                                                                  \
    _Pragma("unroll") for (int j_ = 0; j_ < 2; ++j_) {                                  \
      const u16* g_ = GB + (KEL) + offB[S_][j_];                                        \
      lptr_t l_ = (lptr_t)&B_sh[BUF][ldsB[S_][j_]];                                     \
      __builtin_amdgcn_global_load_lds((gptr_t)g_,                                      \
                                       (__attribute__((address_space(3))) void*)l_,     \
                                       16, 0, 0);                                       \
    }                                                                                   \
  } while (0)

#define RD_A(BUF, MS, DST)                                                              \
  do {                                                                                  \
    const int rb_ = wr * 128 + (MS) * 64;                                               \
    _Pragma("unroll") for (int m_ = 0; m_ < 4; ++m_)                                    \
    _Pragma("unroll") for (int kk_ = 0; kk_ < 2; ++kk_)                                 \
      DST[m_][kk_] = *(const v8s*)&A_sh[BUF][(rb_ + m_ * 16 + l16) * 64 + colR[kk_]];   \
  } while (0)

#define RD_B(BUF, NS)                                                                   \
  do {                                                                                  \
    const int rb_ = wc * 64 + (NS) * 32;                                                \
    _Pragma("unroll") for (int n_ = 0; n_ < 2; ++n_)                                    \
    _Pragma("unroll") for (int kk_ = 0; kk_ < 2; ++kk_)                                 \
      b[n_][kk_] = *(const v8s*)&B_sh[BUF][(rb_ + n_ * 16 + l16) * 64 + colR[kk_]];     \
  } while (0)

#define MM(AR, MS, NS)                                                                  \
  do {                                                                                  \
    __builtin_amdgcn_s_setprio(1);                                                      \
    _Pragma("unroll") for (int kk_ = 0; kk_ < 2; ++kk_)                                 \
    _Pragma("unroll") for (int m_ = 0; m_ < 4; ++m_)                                    \
    _Pragma("unroll") for (int n_ = 0; n_ < 2; ++n_)                                    \
      acc[(MS) * 4 + m_][(NS) * 2 + n_] = __builtin_amdgcn_mfma_f32_16x16x32_bf16(      \
          AR[m_][kk_], b[n_][kk_], acc[(MS) * 4 + m_][(NS) * 2 + n_], 0, 0, 0);         \
    __builtin_amdgcn_s_setprio(0);                                                      \
  } while (0)

#define PHASE_MID()                                                                     \
  do {                                                                                  \
    asm volatile("" ::: "memory");                                                      \
    __builtin_amdgcn_s_barrier();                                                       \
    asm volatile("s_waitcnt lgkmcnt(0)" ::: "memory");                                  \
    __builtin_amdgcn_sched_barrier(0);                                                  \
  } while (0)

#define PHASE_END()                                                                     \
  do {                                                                                  \
    asm volatile("" ::: "memory");                                                      \
    __builtin_amdgcn_s_barrier();                                                       \
    __builtin_amdgcn_sched_barrier(0);                                                  \
  } while (0)

#define PHASE_END_V()                                                                   \
  do {                                                                                  \
    asm volatile("s_waitcnt vmcnt(6)" ::: "memory");                                    \
    __builtin_amdgcn_s_barrier();                                                       \
    __builtin_amdgcn_sched_barrier(0);                                                  \
  } while (0)

  v4f acc[8][4] = {};
  v8s a0[4][2], a1[4][2], b[2][2];

  // ---- prologue: kt0 fully (Aa,Bg,Ab,Bd) + kt1 (Bg,Ab,Bd); Aa(kt1) at P1.
  ST_A(0, 0, 0); ST_B(0, 0, 0); ST_A(0, 0, 1); ST_B(0, 0, 1);
  ST_B(1, 64, 0); ST_A(1, 64, 1); ST_B(1, 64, 1);
  asm volatile("s_waitcnt vmcnt(6)" ::: "memory");   // kt0's 8 loads landed
  __builtin_amdgcn_s_barrier();
  __builtin_amdgcn_sched_barrier(0);

  for (int it = 0; it < 16; ++it) {
    const int k1 = (2 * it + 1) * 64;            // <= 31*64, never wraps
    const int k2 = ((2 * it + 2) & 31) * 64;     // wraps harmlessly on it=15
    const int k3 = ((2 * it + 3) & 31) * 64;
    // ---- K-tile 2it (buf0)
    RD_A(0, 0, a0); RD_B(0, 0); ST_A(1, k1, 0); PHASE_MID(); MM(a0, 0, 0); PHASE_END();
    RD_A(0, 1, a1);             ST_B(0, k2, 0); PHASE_MID(); MM(a1, 1, 0); PHASE_END();
    RD_B(0, 1);                 ST_A(0, k2, 1); PHASE_MID(); MM(a1, 1, 1); PHASE_END();
                                ST_B(0, k2, 1); PHASE_MID(); MM(a0, 0, 1); PHASE_END_V();
    // ---- K-tile 2it+1 (buf1)
    RD_A(1, 0, a0); RD_B(1, 0); ST_A(0, k2, 0); PHASE_MID(); MM(a0, 0, 0); PHASE_END();
    RD_A(1, 1, a1);             ST_B(1, k3, 0); PHASE_MID(); MM(a1, 1, 0); PHASE_END();
    RD_B(1, 1);                 ST_A(1, k3, 1); PHASE_MID(); MM(a1, 1, 1); PHASE_END();
                                ST_B(1, k3, 1); PHASE_MID(); MM(a0, 0, 1); PHASE_END_V();
  }

#undef ST_A
#undef ST_B
#undef RD_A
#undef RD_B
#undef MM
#undef PHASE_MID
#undef PHASE_END
#undef PHASE_END_V

  // ---- epilogue: bias + per-region store (same mapping as before)
#pragma unroll
  for (int n = 0; n < 4; ++n) {
    int nl = nloc0 + wc * 64 + n * 16 + l16;
    float bvl = bias[nl];
    if (region == 0) {
#pragma unroll
      for (int m = 0; m < 8; ++m)
#pragma unroll
        for (int r = 0; r < 4; ++r) {
          int mg = m0 + wr * 128 + m * 16 + quad * 4 + r;
          qp[(size_t)mg * 2048 + nl] = f2b((acc[m][n][r] + bvl) * 0.08838834764831845f);
        }
    } else if (region == 1) {
#pragma unroll
      for (int m = 0; m < 8; ++m)
#pragma unroll
        for (int r = 0; r < 4; ++r) {
          int mg = m0 + wr * 128 + m * 16 + quad * 4 + r;
          kp[(size_t)mg * 1024 + nl] = f2b(acc[m][n][r] + bvl);
        }
    } else {
      int g = nl >> 7, d = nl & 127;
#pragma unroll
      for (int m = 0; m < 8; ++m) {
        int mb = m0 + wr * 128 + m * 16 + quad * 4;
        int bb = mb >> 11, s = mb & 2047;
        ushort4 pk;
        pk.x = f2b(acc[m][n][0] + bvl);
        pk.y = f2b(acc[m][n][1] + bvl);
        pk.z = f2b(acc[m][n][2] + bvl);
        pk.w = f2b(acc[m][n][3] + bvl);
        *(ushort4*)&vpt[(((size_t)bb * 8 + g) * 128 + d) * 2048 + s] = pk;
      }
    }
  }
}

// =========================================================================
// GQA attention v2 — unchanged (3-bit swizzle already in place).
// =========================================================================
__global__ __launch_bounds__(256, 2) void gqa_attn2(const u16* __restrict__ qp,
                                                    const u16* __restrict__ kp,
                                                    const u16* __restrict__ vpt,
                                                    float* __restrict__ out) {
  __shared__ __align__(16) u16 K_sh[2][64 * 128];
  __shared__ __align__(16) u16 V_sh[2][128 * 64];

  const int qtile = blockIdx.x;   // 16 tiles of 128 q-rows
  const int head = blockIdx.y;    // 16
  const int batch = blockIdx.z;   // 2
  const int g = head >> 1;
  const int q0 = qtile * 128;

  const u16* qpb = qp + (size_t)batch * 2048 * 2048;
  const u16* kpb = kp + (size_t)batch * 2048 * 1024;
  const u16* vptb = vpt + (size_t)batch * 8 * 128 * 2048;
  float* outb = out + (size_t)batch * 2048 * 2048;

  const int t = threadIdx.x;
  const int wave = t >> 6, lane = t & 63;
  const int l = lane & 31, h = lane >> 5;

  v8s qf[8];
  {
    const u16* qrow = &qpb[(size_t)(q0 + wave * 32 + l) * 2048 + head * 128];
#pragma unroll
    for (int ks = 0; ks < 8; ++ks)
      qf[ks] = *(const v8s*)&qrow[ks * 16 + h * 8];
  }

  int colK[8];
#pragma unroll
  for (int ks = 0; ks < 8; ++ks) colK[ks] = ((2 * ks + h) ^ (l & 7)) * 8;

  int koff[4], voff[4];
#pragma unroll
  for (int i = 0; i < 4; ++i) {
    int krow = wave * 16 + i * 4 + (lane >> 4);
    int kg = (lane & 15) ^ (krow & 7);
    koff[i] = krow * 1024 + g * 128 + kg * 8;
    int vrow = wave * 32 + i * 8 + (lane >> 3);
    int vg = (lane & 7) ^ (vrow & 7);
    voff[i] = (g * 128 + vrow) * 2048 + vg * 8;
  }

#define STAGE_KV(BUF, S0)                                                               \
  do {                                                                                  \
    _Pragma("unroll") for (int i_ = 0; i_ < 4; ++i_) {                                  \
      const u16* gk_ = kpb + (size_t)(S0) * 1024 + koff[i_];                            \
      lptr_t lk_ = (lptr_t)&K_sh[BUF][(wave * 16 + i_ * 4) * 128] + lane * 8;           \
      __builtin_amdgcn_global_load_lds((gptr_t)gk_,                                     \
                                       (__attribute__((address_space(3))) void*)lk_,    \
                                       16, 0, 0);                                       \
      const u16* gv_ = vptb + voff[i_] + (S0);                                          \
      lptr_t lv_ = (lptr_t)&V_sh[BUF][(wave * 32 + i_ * 8) * 64] + lane * 8;            \
      __builtin_amdgcn_global_load_lds((gptr_t)gv_,                                     \
                                       (__attribute__((address_space(3))) void*)lv_,    \
                                       16, 0, 0);                                       \
    }                                                                                   \
  } while (0)

  v16f o_acc[4] = {};
  float rs = 0.0f;

  STAGE_KV(0, 0);
  __syncthreads();

  int cur = 0;
  for (int sc = 0; sc < 32; ++sc) {
    if (sc < 31) STAGE_KV(cur ^ 1, (sc + 1) * 64);

    v16f sacc[2] = {};
    __builtin_amdgcn_s_setprio(1);
#pragma unroll
    for (int kb = 0; kb < 2; ++kb)
#pragma unroll
      for (int ks = 0; ks < 8; ++ks) {
        v8s kf = *(const v8s*)&K_sh[cur][(kb * 32 + l) * 128 + colK[ks]];
        sacc[kb] = __builtin_amdgcn_mfma_f32_32x32x16_bf16(kf, qf[ks], sacc[kb], 0, 0, 0);
      }
    __builtin_amdgcn_s_setprio(0);

    unsigned int wv[16];
#pragma unroll
    for (int kb = 0; kb < 2; ++kb)
#pragma unroll
      for (int p = 0; p < 8; ++p) {
        float e0 = __expf(sacc[kb][2 * p]);
        float e1 = __expf(sacc[kb][2 * p + 1]);
        rs += e0 + e1;
        asm("v_cvt_pk_bf16_f32 %0, %1, %2" : "=v"(wv[kb * 8 + p]) : "v"(e0), "v"(e1));
      }

    v8s pa[4];
#pragma unroll
    for (int j = 0; j < 4; ++j) {
      unsigned int a = wv[j * 4 + 0], c = wv[j * 4 + 1];
      unsigned int b = wv[j * 4 + 2], d = wv[j * 4 + 3];
      asm("v_permlane32_swap_b32 %0, %1" : "+v"(a), "+v"(b));
      asm("v_permlane32_swap_b32 %0, %1" : "+v"(c), "+v"(d));
      union { unsigned int u[4]; v8s s; } pk;
      pk.u[0] = a; pk.u[1] = c; pk.u[2] = b; pk.u[3] = d;
      pa[j] = pk.s;
    }

    __builtin_amdgcn_s_setprio(1);
#pragma unroll
    for (int j = 0; j < 4; ++j)
#pragma unroll
      for (int db = 0; db < 4; ++db) {
        v8s vf = *(const v8s*)&V_sh[cur][(db * 32 + l) * 64 + colK[j]];
        o_acc[db] = __builtin_amdgcn_mfma_f32_32x32x16_bf16(pa[j], vf, o_acc[db], 0, 0, 0);
      }
    __builtin_amdgcn_s_setprio(0);

    __syncthreads();
    cur ^= 1;
  }

  float rst = rs + __shfl_xor(rs, 32, 64);
  float inv = 1.0f / rst;
#pragma unroll
  for (int r = 0; r < 16; ++r) {
    int qpat = (r & 3) + 8 * (r >> 2) + 4 * h;
    float invq = __shfl(inv, qpat, 64);
    int qrow = q0 + wave * 32 + qpat;
    float* orow = &outb[(size_t)qrow * 2048 + head * 128 + l];
#pragma unroll
    for (int db = 0; db < 4; ++db)
      orow[db * 32] = o_acc[db][r] * invq;
  }
#undef STAGE_KV
}

// =========================================================================
extern "C" void kernel_launch(void* const* d_in, const int* in_sizes, int n_in,
                              void* d_out, int out_size, void* d_ws, size_t ws_size,
                              hipStream_t stream) {
  const float* q  = (const float*)d_in[0];
  const float* k  = (const float*)d_in[1];
  const float* v  = (const float*)d_in[2];
  const float* Wq = (const float*)d_in[3];
  const float* bq = (const float*)d_in[4];
  const float* Wk = (const float*)d_in[5];
  const float* bk = (const float*)d_in[6];
  const float* Wv = (const float*)d_in[7];
  const float* bv = (const float*)d_in[8];
  float* out = (float*)d_out;
  char* ws = (char*)d_ws;

  u16* qbf    = (u16*)(ws + 0);          // [4096][2048] bf16
  u16* kbf    = (u16*)(ws + 16777216);
  u16* vbf    = (u16*)(ws + 33554432);
  u16* wt_all = (u16*)(ws + 50331648);   // [4096][2048] (Wq^T|Wk^T|Wv^T)
  u16* qp     = (u16*)(ws + 67108864);   // [4096][2048] (Q pre-scaled)
  u16* kp     = (u16*)(ws + 83886080);   // [4096][1024]
  u16* vpt    = (u16*)(ws + 92274688);   // [2][8][128][2048]

  conv3_bf16<<<12288, 256, 0, stream>>>(q, k, v, qbf, kbf, vbf);
  transp3_w<<<2048, 256, 0, stream>>>(Wq, Wk, Wv, wt_all);
  qkv_gemm8<<<256, 512, 0, stream>>>(qbf, kbf, vbf, wt_all,
                                     bq, bk, bv, qp, kp, vpt);
  gqa_attn2<<<dim3(16, 16, 2), 256, 0, stream>>>(qp, kp, vpt, out);
}

// Round 6
// 316.257 us; speedup vs baseline: 1.0687x; 1.0127x over previous
//
#include <hip/hip_runtime.h>

typedef unsigned short u16;
typedef short v8s __attribute__((ext_vector_type(8)));
typedef float v4f __attribute__((ext_vector_type(4)));
typedef float v16f __attribute__((ext_vector_type(16)));

typedef __attribute__((address_space(3))) u16* lptr_t;
typedef const __attribute__((address_space(1))) void* gptr_t;

__device__ __forceinline__ u16 f2b(float f) {
  unsigned int u = __float_as_uint(f);
  u += 0x7fff + ((u >> 16) & 1);   // RNE
  return (u16)(u >> 16);
}

// =========================================================================
// Fused preprocessing: blocks 0..12287 = fp32->bf16 conversion of q,k,v;
// blocks 12288..14335 = the three weight transposes. (Kept from round 5 —
// pure block-range fusion of two proven bodies, disjoint reads/writes.)
// =========================================================================
__global__ __launch_bounds__(256) void prep_all(const float* __restrict__ q,
                                                const float* __restrict__ k,
                                                const float* __restrict__ v,
                                                const float* __restrict__ Wq,
                                                const float* __restrict__ Wk,
                                                const float* __restrict__ Wv,
                                                u16* __restrict__ qd,
                                                u16* __restrict__ kd,
                                                u16* __restrict__ vd,
                                                u16* __restrict__ wt) {
  __shared__ u16 tile[64][65];
  int blk = blockIdx.x;
  if (blk < 12288) {
    const float* s; u16* d;
    if (blk < 4096)      { s = q; d = qd; }
    else if (blk < 8192) { s = k; d = kd; blk -= 4096; }
    else                 { s = v; d = vd; blk -= 8192; }
    int i = (blk * 256 + threadIdx.x) * 8;
    float4 a = *(const float4*)&s[i];
    float4 b = *(const float4*)&s[i + 4];
    union { uint4 v4; u16 u[8]; } p;
    p.u[0] = f2b(a.x); p.u[1] = f2b(a.y); p.u[2] = f2b(a.z); p.u[3] = f2b(a.w);
    p.u[4] = f2b(b.x); p.u[5] = f2b(b.y); p.u[6] = f2b(b.z); p.u[7] = f2b(b.w);
    *(uint4*)&d[i] = p.v4;
    return;
  }
  blk -= 12288;
  const float* W; int N; u16* dst;
  if (blk < 1024)      { W = Wq; N = 2048; dst = wt; }
  else if (blk < 1536) { W = Wk; N = 1024; dst = wt + (size_t)2048 * 2048; blk -= 1024; }
  else                 { W = Wv; N = 1024; dst = wt + (size_t)3072 * 2048; blk -= 1536; }
  const int k0 = (blk & 31) * 64;
  const int n0 = (blk >> 5) * 64;
  const int t = threadIdx.x;
#pragma unroll
  for (int i = 0; i < 2; ++i) {
    int chunk = i * 256 + t;
    int kr = chunk >> 3;
    int nc = (chunk & 7) * 8;
    float4 a = *(const float4*)&W[(size_t)(k0 + kr) * N + n0 + nc];
    float4 b = *(const float4*)&W[(size_t)(k0 + kr) * N + n0 + nc + 4];
    tile[kr][nc + 0] = f2b(a.x); tile[kr][nc + 1] = f2b(a.y);
    tile[kr][nc + 2] = f2b(a.z); tile[kr][nc + 3] = f2b(a.w);
    tile[kr][nc + 4] = f2b(b.x); tile[kr][nc + 5] = f2b(b.y);
    tile[kr][nc + 6] = f2b(b.z); tile[kr][nc + 7] = f2b(b.w);
  }
  __syncthreads();
#pragma unroll
  for (int i = 0; i < 2; ++i) {
    int chunk = i * 256 + t;
    int nr = chunk >> 3;
    int kc = (chunk & 7) * 8;
    union { uint4 v; u16 u[8]; } cv;
#pragma unroll
    for (int j = 0; j < 8; ++j) cv.u[j] = tile[kc + j][nr];
    *(uint4*)&dst[(size_t)(n0 + nr) * 2048 + k0 + kc] = cv.v;
  }
}

// =========================================================================
// Fused QKV projection GEMM — unchanged from round 4 (256x256, BK=64,
// 8-phase, full 3-bit XOR swizzle, dedicated a0/a1 register sets).
// =========================================================================
__global__ __launch_bounds__(512, 2) void qkv_gemm8(const u16* __restrict__ qbf,
                                                    const u16* __restrict__ kbf,
                                                    const u16* __restrict__ vbf,
                                                    const u16* __restrict__ wt_all,
                                                    const float* __restrict__ bq,
                                                    const float* __restrict__ bk,
                                                    const float* __restrict__ bv,
                                                    u16* __restrict__ qp,
                                                    u16* __restrict__ kp,
                                                    u16* __restrict__ vpt) {
  __shared__ __align__(16) u16 A_sh[2][16384];   // [buf][256*64]
  __shared__ __align__(16) u16 B_sh[2][16384];

  const int bid = blockIdx.x;                 // 256 blocks
  const int wg = (bid & 7) * 32 + (bid >> 3); // XCD-chunked swizzle (256%8==0)
  const int m0 = (wg >> 4) * 256;
  const int n0 = (wg & 15) * 256;

  const int t = threadIdx.x;
  const int w = t >> 6, lane = t & 63;
  const int quad = lane >> 4, l16 = lane & 15;
  const int wr = w >> 2, wc = w & 3;          // 2 x 4 wave grid

  const u16* Abase; const float* bias; int region, nloc0;
  if (n0 < 2048)      { Abase = qbf; bias = bq; region = 0; nloc0 = n0; }
  else if (n0 < 3072) { Abase = kbf; bias = bk; region = 1; nloc0 = n0 - 2048; }
  else                { Abase = vbf; bias = bv; region = 2; nloc0 = n0 - 3072; }

  const u16* GA = Abase + (size_t)m0 * 2048;
  const u16* GB = wt_all + (size_t)n0 * 2048;

  int offA[2][2], ldsA[2][2], offB[2][2], ldsB[2][2];
#pragma unroll
  for (int s_ = 0; s_ < 2; ++s_)
#pragma unroll
    for (int j = 0; j < 2; ++j) {
      int r0a = j * 128 + s_ * 64 + w * 8;
      int ra = r0a + (lane >> 3);
      offA[s_][j] = ra * 2048 + (((lane & 7) ^ (ra & 7)) << 3);
      ldsA[s_][j] = r0a * 64 + lane * 8;
      int r0b = j * 128 + s_ * 32 + (w >> 2) * 64 + (w & 3) * 8;
      int rb = r0b + (lane >> 3);
      offB[s_][j] = rb * 2048 + (((lane & 7) ^ (rb & 7)) << 3);
      ldsB[s_][j] = r0b * 64 + lane * 8;
    }

  int colR[2];
#pragma unroll
  for (int kk = 0; kk < 2; ++kk)
    colR[kk] = ((kk * 4 + quad) ^ (l16 & 7)) << 3;

#define ST_A(BUF, KEL, S_)                                                              \
  do {                                                                                  \
    _Pragma("unroll") for (int j_ = 0; j_ < 2; ++j_) {                                  \
      const u16* g_ = GA + (KEL) + offA[S_][j_];                                        \
      lptr_t l_ = (lptr_t)&A_sh[BUF][ldsA[S_][j_]];                                     \
      __builtin_amdgcn_global_load_lds((gptr_t)g_,                                      \
                                       (__attribute__((address_space(3))) void*)l_,     \
                                       16, 0, 0);                                       \
    }                                                                                   \
  } while (0)

#define ST_B(BUF, KEL, S_)                                                              \
  do {                                                                                  \
    _Pragma("unroll") for (int j_ = 0; j_ < 2; ++j_) {                                  \
      const u16* g_ = GB + (KEL) + offB[S_][j_];                                        \
      lptr_t l_ = (lptr_t)&B_sh[BUF][ldsB[S_][j_]];                                     \
      __builtin_amdgcn_global_load_lds((gptr_t)g_,                                      \
                                       (__attribute__((address_space(3))) void*)l_,     \
                                       16, 0, 0);                                       \
    }                                                                                   \
  } while (0)

#define RD_A(BUF, MS, DST)                                                              \
  do {                                                                                  \
    const int rb_ = wr * 128 + (MS) * 64;                                               \
    _Pragma("unroll") for (int m_ = 0; m_ < 4; ++m_)                                    \
    _Pragma("unroll") for (int kk_ = 0; kk_ < 2; ++kk_)                                 \
      DST[m_][kk_] = *(const v8s*)&A_sh[BUF][(rb_ + m_ * 16 + l16) * 64 + colR[kk_]];   \
  } while (0)

#define RD_B(BUF, NS)                                                                   \
  do {                                                                                  \
    const int rb_ = wc * 64 + (NS) * 32;                                                \
    _Pragma("unroll") for (int n_ = 0; n_ < 2; ++n_)                                    \
    _Pragma("unroll") for (int kk_ = 0; kk_ < 2; ++kk_)                                 \
      b[n_][kk_] = *(const v8s*)&B_sh[BUF][(rb_ + n_ * 16 + l16) * 64 + colR[kk_]];     \
  } while (0)

#define MM(AR, MS, NS)                                                                  \
  do {                                                                                  \
    __builtin_amdgcn_s_setprio(1);                                                      \
    _Pragma("unroll") for (int kk_ = 0; kk_ < 2; ++kk_)                                 \
    _Pragma("unroll") for (int m_ = 0; m_ < 4; ++m_)                                    \
    _Pragma("unroll") for (int n_ = 0; n_ < 2; ++n_)                                    \
      acc[(MS) * 4 + m_][(NS) * 2 + n_] = __builtin_amdgcn_mfma_f32_16x16x32_bf16(      \
          AR[m_][kk_], b[n_][kk_], acc[(MS) * 4 + m_][(NS) * 2 + n_], 0, 0, 0);         \
    __builtin_amdgcn_s_setprio(0);                                                      \
  } while (0)

#define PHASE_MID()                                                                     \
  do {                                                                                  \
    asm volatile("" ::: "memory");                                                      \
    __builtin_amdgcn_s_barrier();                                                       \
    asm volatile("s_waitcnt lgkmcnt(0)" ::: "memory");                                  \
    __builtin_amdgcn_sched_barrier(0);                                                  \
  } while (0)

#define PHASE_END()                                                                     \
  do {                                                                                  \
    asm volatile("" ::: "memory");                                                      \
    __builtin_amdgcn_s_barrier();                                                       \
    __builtin_amdgcn_sched_barrier(0);                                                  \
  } while (0)

#define PHASE_END_V()                                                                   \
  do {                                                                                  \
    asm volatile("s_waitcnt vmcnt(6)" ::: "memory");                                    \
    __builtin_amdgcn_s_barrier();                                                       \
    __builtin_amdgcn_sched_barrier(0);                                                  \
  } while (0)

  v4f acc[8][4] = {};
  v8s a0[4][2], a1[4][2], b[2][2];

  ST_A(0, 0, 0); ST_B(0, 0, 0); ST_A(0, 0, 1); ST_B(0, 0, 1);
  ST_B(1, 64, 0); ST_A(1, 64, 1); ST_B(1, 64, 1);
  asm volatile("s_waitcnt vmcnt(6)" ::: "memory");   // kt0's 8 loads landed
  __builtin_amdgcn_s_barrier();
  __builtin_amdgcn_sched_barrier(0);

  for (int it = 0; it < 16; ++it) {
    const int k1 = (2 * it + 1) * 64;
    const int k2 = ((2 * it + 2) & 31) * 64;
    const int k3 = ((2 * it + 3) & 31) * 64;
    // ---- K-tile 2it (buf0)
    RD_A(0, 0, a0); RD_B(0, 0); ST_A(1, k1, 0); PHASE_MID(); MM(a0, 0, 0); PHASE_END();
    RD_A(0, 1, a1);             ST_B(0, k2, 0); PHASE_MID(); MM(a1, 1, 0); PHASE_END();
    RD_B(0, 1);                 ST_A(0, k2, 1); PHASE_MID(); MM(a1, 1, 1); PHASE_END();
                                ST_B(0, k2, 1); PHASE_MID(); MM(a0, 0, 1); PHASE_END_V();
    // ---- K-tile 2it+1 (buf1)
    RD_A(1, 0, a0); RD_B(1, 0); ST_A(0, k2, 0); PHASE_MID(); MM(a0, 0, 0); PHASE_END();
    RD_A(1, 1, a1);             ST_B(1, k3, 0); PHASE_MID(); MM(a1, 1, 0); PHASE_END();
    RD_B(1, 1);                 ST_A(1, k3, 1); PHASE_MID(); MM(a1, 1, 1); PHASE_END();
                                ST_B(1, k3, 1); PHASE_MID(); MM(a0, 0, 1); PHASE_END_V();
  }

#undef ST_A
#undef ST_B
#undef RD_A
#undef RD_B
#undef MM
#undef PHASE_MID
#undef PHASE_END
#undef PHASE_END_V

#pragma unroll
  for (int n = 0; n < 4; ++n) {
    int nl = nloc0 + wc * 64 + n * 16 + l16;
    float bvl = bias[nl];
    if (region == 0) {
#pragma unroll
      for (int m = 0; m < 8; ++m)
#pragma unroll
        for (int r = 0; r < 4; ++r) {
          int mg = m0 + wr * 128 + m * 16 + quad * 4 + r;
          qp[(size_t)mg * 2048 + nl] = f2b((acc[m][n][r] + bvl) * 0.08838834764831845f);
        }
    } else if (region == 1) {
#pragma unroll
      for (int m = 0; m < 8; ++m)
#pragma unroll
        for (int r = 0; r < 4; ++r) {
          int mg = m0 + wr * 128 + m * 16 + quad * 4 + r;
          kp[(size_t)mg * 1024 + nl] = f2b(acc[m][n][r] + bvl);
        }
    } else {
      int g = nl >> 7, d = nl & 127;
#pragma unroll
      for (int m = 0; m < 8; ++m) {
        int mb = m0 + wr * 128 + m * 16 + quad * 4;
        int bb = mb >> 11, s = mb & 2047;
        ushort4 pk;
        pk.x = f2b(acc[m][n][0] + bvl);
        pk.y = f2b(acc[m][n][1] + bvl);
        pk.z = f2b(acc[m][n][2] + bvl);
        pk.w = f2b(acc[m][n][3] + bvl);
        *(ushort4*)&vpt[(((size_t)bb * 8 + g) * 128 + d) * 2048 + s] = pk;
      }
    }
  }
}

// =========================================================================
// GQA attention v2 — EXACT round-4 body restored (passed, 85.7us).
// The round-5 within-chunk reorder is reverted pending a proper race screen.
// =========================================================================
__global__ __launch_bounds__(256, 2) void gqa_attn2(const u16* __restrict__ qp,
                                                    const u16* __restrict__ kp,
                                                    const u16* __restrict__ vpt,
                                                    float* __restrict__ out) {
  __shared__ __align__(16) u16 K_sh[2][64 * 128];
  __shared__ __align__(16) u16 V_sh[2][128 * 64];

  const int qtile = blockIdx.x;   // 16 tiles of 128 q-rows
  const int head = blockIdx.y;    // 16
  const int batch = blockIdx.z;   // 2
  const int g = head >> 1;
  const int q0 = qtile * 128;

  const u16* qpb = qp + (size_t)batch * 2048 * 2048;
  const u16* kpb = kp + (size_t)batch * 2048 * 1024;
  const u16* vptb = vpt + (size_t)batch * 8 * 128 * 2048;
  float* outb = out + (size_t)batch * 2048 * 2048;

  const int t = threadIdx.x;
  const int wave = t >> 6, lane = t & 63;
  const int l = lane & 31, h = lane >> 5;

  v8s qf[8];
  {
    const u16* qrow = &qpb[(size_t)(q0 + wave * 32 + l) * 2048 + head * 128];
#pragma unroll
    for (int ks = 0; ks < 8; ++ks)
      qf[ks] = *(const v8s*)&qrow[ks * 16 + h * 8];
  }

  int colK[8];
#pragma unroll
  for (int ks = 0; ks < 8; ++ks) colK[ks] = ((2 * ks + h) ^ (l & 7)) * 8;

  int koff[4], voff[4];
#pragma unroll
  for (int i = 0; i < 4; ++i) {
    int krow = wave * 16 + i * 4 + (lane >> 4);
    int kg = (lane & 15) ^ (krow & 7);
    koff[i] = krow * 1024 + g * 128 + kg * 8;
    int vrow = wave * 32 + i * 8 + (lane >> 3);
    int vg = (lane & 7) ^ (vrow & 7);
    voff[i] = (g * 128 + vrow) * 2048 + vg * 8;
  }

#define STAGE_KV(BUF, S0)                                                               \
  do {                                                                                  \
    _Pragma("unroll") for (int i_ = 0; i_ < 4; ++i_) {                                  \
      const u16* gk_ = kpb + (size_t)(S0) * 1024 + koff[i_];                            \
      lptr_t lk_ = (lptr_t)&K_sh[BUF][(wave * 16 + i_ * 4) * 128] + lane * 8;           \
      __builtin_amdgcn_global_load_lds((gptr_t)gk_,                                     \
                                       (__attribute__((address_space(3))) void*)lk_,    \
                                       16, 0, 0);                                       \
      const u16* gv_ = vptb + voff[i_] + (S0);                                          \
      lptr_t lv_ = (lptr_t)&V_sh[BUF][(wave * 32 + i_ * 8) * 64] + lane * 8;            \
      __builtin_amdgcn_global_load_lds((gptr_t)gv_,                                     \
                                       (__attribute__((address_space(3))) void*)lv_,    \
                                       16, 0, 0);                                       \
    }                                                                                   \
  } while (0)

  v16f o_acc[4] = {};
  float rs = 0.0f;

  STAGE_KV(0, 0);
  __syncthreads();

  int cur = 0;
  for (int sc = 0; sc < 32; ++sc) {
    if (sc < 31) STAGE_KV(cur ^ 1, (sc + 1) * 64);

    v16f sacc[2] = {};
    __builtin_amdgcn_s_setprio(1);
#pragma unroll
    for (int kb = 0; kb < 2; ++kb)
#pragma unroll
      for (int ks = 0; ks < 8; ++ks) {
        v8s kf = *(const v8s*)&K_sh[cur][(kb * 32 + l) * 128 + colK[ks]];
        sacc[kb] = __builtin_amdgcn_mfma_f32_32x32x16_bf16(kf, qf[ks], sacc[kb], 0, 0, 0);
      }
    __builtin_amdgcn_s_setprio(0);

    unsigned int wv[16];
#pragma unroll
    for (int kb = 0; kb < 2; ++kb)
#pragma unroll
      for (int p = 0; p < 8; ++p) {
        float e0 = __expf(sacc[kb][2 * p]);
        float e1 = __expf(sacc[kb][2 * p + 1]);
        rs += e0 + e1;
        asm("v_cvt_pk_bf16_f32 %0, %1, %2" : "=v"(wv[kb * 8 + p]) : "v"(e0), "v"(e1));
      }

    v8s pa[4];
#pragma unroll
    for (int j = 0; j < 4; ++j) {
      unsigned int a = wv[j * 4 + 0], c = wv[j * 4 + 1];
      unsigned int b = wv[j * 4 + 2], d = wv[j * 4 + 3];
      asm("v_permlane32_swap_b32 %0, %1" : "+v"(a), "+v"(b));
      asm("v_permlane32_swap_b32 %0, %1" : "+v"(c), "+v"(d));
      union { unsigned int u[4]; v8s s; } pk;
      pk.u[0] = a; pk.u[1] = c; pk.u[2] = b; pk.u[3] = d;
      pa[j] = pk.s;
    }

    __builtin_amdgcn_s_setprio(1);
#pragma unroll
    for (int j = 0; j < 4; ++j)
#pragma unroll
      for (int db = 0; db < 4; ++db) {
        v8s vf = *(const v8s*)&V_sh[cur][(db * 32 + l) * 64 + colK[j]];
        o_acc[db] = __builtin_amdgcn_mfma_f32_32x32x16_bf16(pa[j], vf, o_acc[db], 0, 0, 0);
      }
    __builtin_amdgcn_s_setprio(0);

    __syncthreads();
    cur ^= 1;
  }

  float rst = rs + __shfl_xor(rs, 32, 64);
  float inv = 1.0f / rst;
#pragma unroll
  for (int r = 0; r < 16; ++r) {
    int qpat = (r & 3) + 8 * (r >> 2) + 4 * h;
    float invq = __shfl(inv, qpat, 64);
    int qrow = q0 + wave * 32 + qpat;
    float* orow = &outb[(size_t)qrow * 2048 + head * 128 + l];
#pragma unroll
    for (int db = 0; db < 4; ++db)
      orow[db * 32] = o_acc[db][r] * invq;
  }
#undef STAGE_KV
}

// =========================================================================
extern "C" void kernel_launch(void* const* d_in, const int* in_sizes, int n_in,
                              void* d_out, int out_size, void* d_ws, size_t ws_size,
                              hipStream_t stream) {
  const float* q  = (const float*)d_in[0];
  const float* k  = (const float*)d_in[1];
  const float* v  = (const float*)d_in[2];
  const float* Wq = (const float*)d_in[3];
  const float* bq = (const float*)d_in[4];
  const float* Wk = (const float*)d_in[5];
  const float* bk = (const float*)d_in[6];
  const float* Wv = (const float*)d_in[7];
  const float* bv = (const float*)d_in[8];
  float* out = (float*)d_out;
  char* ws = (char*)d_ws;

  u16* qbf    = (u16*)(ws + 0);          // [4096][2048] bf16
  u16* kbf    = (u16*)(ws + 16777216);
  u16* vbf    = (u16*)(ws + 33554432);
  u16* wt_all = (u16*)(ws + 50331648);   // [4096][2048] (Wq^T|Wk^T|Wv^T)
  u16* qp     = (u16*)(ws + 67108864);   // [4096][2048] (Q pre-scaled)
  u16* kp     = (u16*)(ws + 83886080);   // [4096][1024]
  u16* vpt    = (u16*)(ws + 92274688);   // [2][8][128][2048]

  prep_all<<<14336, 256, 0, stream>>>(q, k, v, Wq, Wk, Wv, qbf, kbf, vbf, wt_all);
  qkv_gemm8<<<256, 512, 0, stream>>>(qbf, kbf, vbf, wt_all,
                                     bq, bk, bv, qp, kp, vpt);
  gqa_attn2<<<dim3(16, 16, 2), 256, 0, stream>>>(qp, kp, vpt, out);
}